// Round 4
// baseline (643.625 us; speedup 1.0000x reference)
//
#include <hip/hip_runtime.h>

typedef unsigned int uint_t;
typedef unsigned short ushort_t;

using f32x4 = __attribute__((ext_vector_type(4))) float;
using bf16x8 = __attribute__((ext_vector_type(8))) short;

#define D_MODEL 2048
#define N_HEADS 16
#define N_KV    4
#define HD      128
#define KV_DIM  (N_KV * HD)          // 512
#define NQKV    (D_MODEL + 2*KV_DIM) // 3072
#define SEQ     2048
#define NB      4
#define MROWS   (NB * SEQ)           // 8192
#define SM_SCALE 0.08838834764831845f  // 1/sqrt(128)

__device__ __forceinline__ ushort_t f2bf(float f) {
    uint_t u = __float_as_uint(f);
    u = (u + 0x7FFFu + ((u >> 16) & 1u)) >> 16;   // RNE
    return (ushort_t)u;
}

// async global->LDS, 16 B/lane, lands at (wave-uniform lds base) + lane*16
__device__ __forceinline__ void gload16(const ushort_t* g, ushort_t* l) {
    __builtin_amdgcn_global_load_lds(
        (const __attribute__((address_space(1))) unsigned int*)g,
        (__attribute__((address_space(3))) unsigned int*)l, 16, 0, 0);
}

// ---------------------------------------------------------------- conv_x
__global__ __launch_bounds__(256) void conv_x_kernel(const float* __restrict__ in,
                                                     ushort_t* __restrict__ out, int n) {
    int i = (blockIdx.x * 256 + threadIdx.x) * 4;
    if (i >= n) return;
    float4 v = *(const float4*)&in[i];
    ushort_t o[4] = {f2bf(v.x), f2bf(v.y), f2bf(v.z), f2bf(v.w)};
    *(uint2*)&out[i] = *(uint2*)o;
}

// ------------------------------------------------------ transpose + cast
// W [K][Nout] fp32 -> WT [Nout][K] bf16
__global__ __launch_bounds__(256) void conv_wt_kernel(const float* __restrict__ W,
                                                      ushort_t* __restrict__ WT,
                                                      int K, int Nout) {
    __shared__ float tile[32][33];
    int n0 = blockIdx.x * 32, k0 = blockIdx.y * 32;
    int tx = threadIdx.x, ty = threadIdx.y;  // (32, 8)
    for (int i = 0; i < 4; ++i)
        tile[ty + 8*i][tx] = W[(size_t)(k0 + ty + 8*i) * Nout + n0 + tx];
    __syncthreads();
    for (int i = 0; i < 4; ++i)
        WT[(size_t)(n0 + ty + 8*i) * K + k0 + tx] = f2bf(tile[tx][ty + 8*i]);
}

// ------------------------------------ GEMM staging + double-buffered loop
#define GEMM_STAGE(A, BT, k0, b)                                                   \
    for (int i = 0; i < 4; ++i) {                                                  \
        int ci = (w * 4 + i) * 64 + lane;                                          \
        int row = ci >> 3, c = ci & 7, cg = c ^ (row & 7);                         \
        gload16(&A [(size_t)(bm + row) * K + (k0) + cg * 8], &As[b][0][0] + (w * 4 + i) * 512); \
        gload16(&BT[(size_t)(bn + row) * K + (k0) + cg * 8], &Bs[b][0][0] + (w * 4 + i) * 512); \
    }

#define GEMM_MAIN_LOOP(A, BT, K)                                                   \
    GEMM_STAGE(A, BT, 0, 0)                                                        \
    {                                                                              \
        int buf = 0;                                                               \
        for (int k0 = 0; k0 < K; k0 += 64) {                                       \
            __syncthreads();            /* drains prefetch into As[buf] */         \
            if (k0 + 64 < K) { GEMM_STAGE(A, BT, k0 + 64, buf ^ 1) }               \
            for (int kk = 0; kk < 64; kk += 32) {                                  \
                bf16x8 af[4], bfr[4];                                              \
                int k4 = kk >> 3;                                                  \
                for (int i = 0; i < 4; ++i)                                        \
                    af[i]  = *(const bf16x8*)&As[buf][mb + i * 16 + r][((k4 + quad) ^ (r & 7)) * 8]; \
                for (int j = 0; j < 4; ++j)                                        \
                    bfr[j] = *(const bf16x8*)&Bs[buf][nb + j * 16 + r][((k4 + quad) ^ (r & 7)) * 8]; \
                for (int i = 0; i < 4; ++i)                                        \
                    for (int j = 0; j < 4; ++j)                                    \
                        acc[i][j] = __builtin_amdgcn_mfma_f32_16x16x32_bf16(af[i], bfr[j], acc[i][j], 0, 0, 0); \
            }                                                                      \
            buf ^= 1;                                                              \
        }                                                                          \
    }

// ---------------------------------------------------- out-projection GEMM
__global__ __launch_bounds__(256) void gemm_bt_kernel(const ushort_t* __restrict__ A,
                                                      const ushort_t* __restrict__ BT,
                                                      const float* __restrict__ bias,
                                                      float* __restrict__ C,
                                                      int M, int N, int K) {
    __shared__ ushort_t As[2][128][64];
    __shared__ ushort_t Bs[2][128][64];
    const int bm = blockIdx.x * 128, bn = blockIdx.y * 128;
    const int t = threadIdx.x;
    const int w = t >> 6, lane = t & 63, quad = lane >> 4, r = lane & 15;
    const int mb = (w >> 1) * 64, nb = (w & 1) * 64;
    f32x4 acc[4][4] = {};
    GEMM_MAIN_LOOP(A, BT, K)
    for (int i = 0; i < 4; ++i)
        for (int j = 0; j < 4; ++j)
            for (int reg = 0; reg < 4; ++reg) {
                int row = bm + mb + i * 16 + quad * 4 + reg;
                int col = bn + nb + j * 16 + r;
                C[(size_t)row * N + col] = acc[i][j][reg] + bias[col];
            }
}

// ------------------------------------- QKV GEMM + fused RMSNorm/rearrange
// N-tile 128 == one head group. g = blockIdx.y: 0..15 -> Q (rmsnorm*q_scale*SM),
// 16..19 -> K (rmsnorm*k_scale), 20..23 -> V transposed directly to Vt [nk][d][l].
__global__ __launch_bounds__(256) void gemm_qkv_kernel(const ushort_t* __restrict__ A,
                                                       const ushort_t* __restrict__ BT,
                                                       const float* __restrict__ bias,
                                                       const float* __restrict__ q_scale,
                                                       const float* __restrict__ k_scale,
                                                       ushort_t* __restrict__ Q,
                                                       ushort_t* __restrict__ Kb,
                                                       ushort_t* __restrict__ Vt) {
    __shared__ ushort_t As[2][128][64];
    __shared__ ushort_t Bs[2][128][64];
    const int K = D_MODEL;
    const int bm = blockIdx.x * 128, bn = blockIdx.y * 128;
    const int t = threadIdx.x;
    const int w = t >> 6, lane = t & 63, quad = lane >> 4, r = lane & 15;
    const int mb = (w >> 1) * 64, nb = (w & 1) * 64;
    f32x4 acc[4][4] = {};
    GEMM_MAIN_LOOP(A, BT, K)

    const int g = blockIdx.y;
    float bj[4];
    for (int j = 0; j < 4; ++j) bj[j] = bias[bn + nb + j * 16 + r];
    for (int i = 0; i < 4; ++i)
        for (int j = 0; j < 4; ++j)
            for (int reg = 0; reg < 4; ++reg) acc[i][j][reg] += bj[j];

    const int n = bm >> 11, lb = bm & 2047;
    if (g < 20) {
        __syncthreads();                              // LDS free; reuse for ssum
        float* ssum = (float*)&As[0][0][0];           // [2][128]
        for (int i = 0; i < 4; ++i)
            for (int reg = 0; reg < 4; ++reg) {
                float p = 0.f;
                for (int j = 0; j < 4; ++j) p += acc[i][j][reg] * acc[i][j][reg];
                p += __shfl_xor(p, 1); p += __shfl_xor(p, 2);
                p += __shfl_xor(p, 4); p += __shfl_xor(p, 8);
                if (r == 0) ssum[(w & 1) * 128 + mb + i * 16 + quad * 4 + reg] = p;
            }
        __syncthreads();
        const float* scp = (g < 16) ? q_scale : k_scale;
        const float smul = (g < 16) ? SM_SCALE : 1.0f;
        float scj[4];
        for (int j = 0; j < 4; ++j) scj[j] = scp[nb + j * 16 + r];
        ushort_t* dst = (g < 16) ? (Q  + (size_t)(n * 16 + g) * SEQ * HD)
                                 : (Kb + (size_t)(n * 4 + g - 16) * SEQ * HD);
        for (int i = 0; i < 4; ++i)
            for (int reg = 0; reg < 4; ++reg) {
                int rl = mb + i * 16 + quad * 4 + reg;
                float ss = ssum[rl] + ssum[128 + rl];
                float iv = rsqrtf(ss * (1.0f / 128.0f) + 1e-6f) * smul;
                size_t lrow = lb + rl;
                for (int j = 0; j < 4; ++j) {
                    int d = nb + j * 16 + r;
                    dst[lrow * HD + d] = f2bf(acc[i][j][reg] * iv * scj[j]);
                }
            }
    } else {
        // V: write transposed directly, packing 4 consecutive l per lane (8 B)
        ushort_t* dstT = Vt + (size_t)(n * 4 + g - 20) * HD * SEQ;
        for (int i = 0; i < 4; ++i)
            for (int j = 0; j < 4; ++j) {
                int d = nb + j * 16 + r;
                ushort_t o[4];
                for (int reg = 0; reg < 4; ++reg) o[reg] = f2bf(acc[i][j][reg]);
                *(uint2*)&dstT[(size_t)d * SEQ + lb + mb + i * 16 + quad * 4] = *(uint2*)o;
            }
    }
}

// --------------------------------------------------- flash causal attention
// grid (8, 16, 4), block 128 (2 waves). Wave owns 64 q-rows (4 strips of 16);
// block tile 128 rows. Paired q-tiles {pid, 15-pid}: 36 steps/block, balanced.
// K double-buffered (prefetch K(ct+1) during QK); V staged during QK, used in PV.
// LDS = 32K (Ks dbuf) + 16K (Vts) + 16K (Ps) = 64 KB -> 2 blocks/CU.
__global__ __launch_bounds__(128, 1) void attn_kernel(const ushort_t* __restrict__ Q,
                                                      const ushort_t* __restrict__ K,
                                                      const ushort_t* __restrict__ Vt,
                                                      ushort_t* __restrict__ Y) {
    const int pid = blockIdx.x, h = blockIdx.y, n = blockIdx.z;
    const int kvh = h >> 2;
    const ushort_t* Qp = Q  + (size_t)(n * N_HEADS + h) * SEQ * HD;
    const ushort_t* Kp = K  + (size_t)(n * N_KV + kvh) * SEQ * HD;
    const ushort_t* Vp = Vt + (size_t)(n * N_KV + kvh) * HD * SEQ;   // [d][l]

    __shared__ ushort_t Ks[2][64][128];  // 32 KB, chunk-swizzled, double-buffered
    __shared__ ushort_t Vts[128][64];    // 16 KB, chunk-swizzled ([d][key])
    __shared__ ushort_t Ps[128][64];     // 16 KB, row-chunk-xor swizzled

    const int t = threadIdx.x, w2 = t >> 6, lane = t & 63, quad = lane >> 4, r = lane & 15;

    for (int rep = 0; rep < 2; ++rep) {
        const int qt = rep ? (15 - pid) : pid;
        const int q0 = qt * 128;

        __syncthreads();   // prev rep's LDS reads done before restaging Ks[0]
        // stage K(0) -> Ks[0]
        for (int i = 0; i < 8; ++i) {
            int ci = (w2 * 8 + i) * 64 + lane;
            int row = ci >> 4, c = ci & 15, cg = c ^ (row & 7);
            gload16(&Kp[(size_t)row * HD + cg * 8], &Ks[0][0][0] + (w2 * 8 + i) * 512);
        }

        // Q fragments straight from global (A-layout is contiguous 16B/lane)
        bf16x8 aq[4][4];
        for (int s = 0; s < 4; ++s)
            for (int kc = 0; kc < 4; ++kc)
                aq[s][kc] = *(const bf16x8*)&Qp[(size_t)(q0 + w2 * 64 + s * 16 + r) * HD + kc * 32 + quad * 8];

        f32x4 oacc[4][8] = {};
        float lsum[4][4] = {};
        const int nct = 2 * qt + 2;
        int buf = 0;

        for (int ct = 0; ct < nct; ++ct) {
            __syncthreads();   // drains K(ct) prefetch; prev PV's Vts reads done
            // stage V(ct) -> Vts (consumed after next barrier, this step)
            for (int i = 0; i < 8; ++i) {
                int ci = (w2 * 8 + i) * 64 + lane;
                int row = ci >> 3, c = ci & 7, cg = c ^ (row & 7);
                gload16(&Vp[(size_t)row * SEQ + ct * 64 + cg * 8], &Vts[0][0] + (w2 * 8 + i) * 512);
            }
            // prefetch K(ct+1) -> Ks[buf^1] (consumed next step)
            if (ct + 1 < nct) {
                for (int i = 0; i < 8; ++i) {
                    int ci = (w2 * 8 + i) * 64 + lane;
                    int row = ci >> 4, c = ci & 15, cg = c ^ (row & 7);
                    gload16(&Kp[(size_t)((ct + 1) * 64 + row) * HD + cg * 8],
                            &Ks[buf ^ 1][0][0] + (w2 * 8 + i) * 512);
                }
            }

            const bool active = (ct <= 2 * qt + w2);   // wave-uniform
            if (active) {
                // S strips [4 x 16 x 64]: QK^T (scale folded into Q)
                f32x4 sacc[4][4] = {};
                for (int kc = 0; kc < 4; ++kc)
                    for (int jt = 0; jt < 4; ++jt) {
                        bf16x8 bk = *(const bf16x8*)&Ks[buf][jt * 16 + r][((kc * 4 + quad) ^ (r & 7)) * 8];
                        for (int s = 0; s < 4; ++s)
                            sacc[s][jt] = __builtin_amdgcn_mfma_f32_16x16x32_bf16(aq[s][kc], bk, sacc[s][jt], 0, 0, 0);
                    }
                // fixed-max softmax; P truncated bf16; row-chunk-xor swizzle
                const bool diag = (ct == 2 * qt + w2);
                for (int s = 0; s < 4; ++s)
                    for (int reg = 0; reg < 4; ++reg) {
                        int prow = w2 * 64 + s * 16 + quad * 4 + reg;
                        int qg = q0 + prow;
                        float rs = 0.f;
                        for (int jt = 0; jt < 4; ++jt) {
                            float sv = sacc[s][jt][reg];
                            if (diag && (ct * 64 + jt * 16 + r) > qg) sv = -1e30f;
                            float p = __expf(sv);
                            rs += p;
                            int colp = ((((jt * 2 + (r >> 3)) ^ prow) & 7) << 3) | (r & 7);
                            Ps[prow][colp] = (ushort_t)(__float_as_uint(p) >> 16);
                        }
                        lsum[s][reg] += rs;
                    }
            }
            __syncthreads();   // drains V(ct) (and K(ct+1)) DMA
            if (active) {
                // PV: O[4x16x128] += P @ V ; bv shared by 4 strips
                for (int kk = 0; kk < 64; kk += 32) {
                    bf16x8 pa[4];
                    for (int s = 0; s < 4; ++s) {
                        int row = w2 * 64 + s * 16 + r;
                        pa[s] = *(const bf16x8*)&Ps[row][((((kk >> 3) + quad) ^ row) & 7) * 8];
                    }
                    for (int dt = 0; dt < 8; ++dt) {
                        bf16x8 bv = *(const bf16x8*)&Vts[dt * 16 + r][((((kk >> 3) + quad) ^ (r & 7)) & 7) * 8];
                        for (int s = 0; s < 4; ++s)
                            oacc[s][dt] = __builtin_amdgcn_mfma_f32_16x16x32_bf16(pa[s], bv, oacc[s][dt], 0, 0, 0);
                    }
                }
            }
            buf ^= 1;
        }

        // epilogue: end-of-loop row-sum reduction, then Y
        for (int s = 0; s < 4; ++s)
            for (int reg = 0; reg < 4; ++reg) {
                float sv = lsum[s][reg];
                for (int m = 1; m < 16; m <<= 1) sv += __shfl_xor(sv, m);
                float invl = 1.0f / sv;
                int lrow = q0 + w2 * 64 + s * 16 + quad * 4 + reg;
                size_t base = ((size_t)(n * SEQ + lrow)) * D_MODEL + h * HD;
                for (int dt = 0; dt < 8; ++dt)
                    Y[base + dt * 16 + r] = f2bf(oacc[s][dt][reg] * invl);
            }
    }
}

// ------------------------------------------------------------------ launch
extern "C" void kernel_launch(void* const* d_in, const int* in_sizes, int n_in,
                              void* d_out, int out_size, void* d_ws, size_t ws_size,
                              hipStream_t stream) {
    const float* x       = (const float*)d_in[0];
    const float* Wqkv    = (const float*)d_in[1];
    const float* bqkv    = (const float*)d_in[2];
    const float* q_scale = (const float*)d_in[3];
    const float* k_scale = (const float*)d_in[4];
    const float* Wout    = (const float*)d_in[5];
    const float* bout    = (const float*)d_in[6];
    float* out = (float*)d_out;

    ushort_t* xb  = (ushort_t*)d_ws;                        // 8192*2048 (later: y)
    ushort_t* WT  = xb  + (size_t)MROWS * D_MODEL;          // 3072*2048 (later: WoutT)
    ushort_t* Qb  = WT  + (size_t)NQKV * D_MODEL;           // 4*16*2048*128
    ushort_t* Kb  = Qb  + (size_t)NB * N_HEADS * SEQ * HD;  // 4*4*2048*128
    ushort_t* Vtb = Kb  + (size_t)NB * N_KV * SEQ * HD;     // 4*4*128*2048

    conv_x_kernel<<<MROWS * D_MODEL / 1024, 256, 0, stream>>>(x, xb, MROWS * D_MODEL);
    conv_wt_kernel<<<dim3(NQKV / 32, D_MODEL / 32), dim3(32, 8), 0, stream>>>(Wqkv, WT, D_MODEL, NQKV);
    gemm_qkv_kernel<<<dim3(MROWS / 128, NQKV / 128), 256, 0, stream>>>(xb, WT, bqkv, q_scale, k_scale, Qb, Kb, Vtb);
    conv_wt_kernel<<<dim3(D_MODEL / 32, D_MODEL / 32), dim3(32, 8), 0, stream>>>(Wout, WT, D_MODEL, D_MODEL);
    attn_kernel<<<dim3(8, N_HEADS, NB), 128, 0, stream>>>(Qb, Kb, Vtb, xb);
    gemm_bt_kernel<<<dim3(MROWS / 128, D_MODEL / 128), 256, 0, stream>>>(xb, WT, bout, out, MROWS, D_MODEL, D_MODEL);
}

// Round 5
// 454.538 us; speedup vs baseline: 1.4160x; 1.4160x over previous
//
#include <hip/hip_runtime.h>

typedef unsigned int uint_t;
typedef unsigned short ushort_t;

using f32x4 = __attribute__((ext_vector_type(4))) float;
using bf16x8 = __attribute__((ext_vector_type(8))) short;

#define D_MODEL 2048
#define N_HEADS 16
#define N_KV    4
#define HD      128
#define KV_DIM  (N_KV * HD)          // 512
#define NQKV    (D_MODEL + 2*KV_DIM) // 3072
#define SEQ     2048
#define NB      4
#define MROWS   (NB * SEQ)           // 8192
#define SM_SCALE 0.08838834764831845f  // 1/sqrt(128)

__device__ __forceinline__ ushort_t f2bf(float f) {
    uint_t u = __float_as_uint(f);
    u = (u + 0x7FFFu + ((u >> 16) & 1u)) >> 16;   // RNE
    return (ushort_t)u;
}

// async global->LDS, 16 B/lane, lands at (wave-uniform lds base) + lane*16
__device__ __forceinline__ void gload16(const ushort_t* g, ushort_t* l) {
    __builtin_amdgcn_global_load_lds(
        (const __attribute__((address_space(1))) unsigned int*)g,
        (__attribute__((address_space(3))) unsigned int*)l, 16, 0, 0);
}

// ---------------------------------------------------------------- conv_x
__global__ __launch_bounds__(256) void conv_x_kernel(const float* __restrict__ in,
                                                     ushort_t* __restrict__ out, int n) {
    int i = (blockIdx.x * 256 + threadIdx.x) * 4;
    if (i >= n) return;
    float4 v = *(const float4*)&in[i];
    ushort_t o[4] = {f2bf(v.x), f2bf(v.y), f2bf(v.z), f2bf(v.w)};
    *(uint2*)&out[i] = *(uint2*)o;
}

// ------------------------------------------------------ transpose + cast
// W [K][Nout] fp32 -> WT [Nout][K] bf16
__global__ __launch_bounds__(256) void conv_wt_kernel(const float* __restrict__ W,
                                                      ushort_t* __restrict__ WT,
                                                      int K, int Nout) {
    __shared__ float tile[32][33];
    int n0 = blockIdx.x * 32, k0 = blockIdx.y * 32;
    int tx = threadIdx.x, ty = threadIdx.y;  // (32, 8)
    for (int i = 0; i < 4; ++i)
        tile[ty + 8*i][tx] = W[(size_t)(k0 + ty + 8*i) * Nout + n0 + tx];
    __syncthreads();
    for (int i = 0; i < 4; ++i)
        WT[(size_t)(n0 + ty + 8*i) * K + k0 + tx] = f2bf(tile[tx][ty + 8*i]);
}

// ------------------------------------ GEMM staging + double-buffered loop
#define GEMM_STAGE(A, BT, k0, b)                                                   \
    for (int i = 0; i < 4; ++i) {                                                  \
        int ci = (w * 4 + i) * 64 + lane;                                          \
        int row = ci >> 3, c = ci & 7, cg = c ^ (row & 7);                         \
        gload16(&A [(size_t)(bm + row) * K + (k0) + cg * 8], &As[b][0][0] + (w * 4 + i) * 512); \
        gload16(&BT[(size_t)(bn + row) * K + (k0) + cg * 8], &Bs[b][0][0] + (w * 4 + i) * 512); \
    }

#define GEMM_MAIN_LOOP(A, BT, K)                                                   \
    GEMM_STAGE(A, BT, 0, 0)                                                        \
    {                                                                              \
        int buf = 0;                                                               \
        for (int k0 = 0; k0 < K; k0 += 64) {                                       \
            __syncthreads();            /* drains prefetch into As[buf] */         \
            if (k0 + 64 < K) { GEMM_STAGE(A, BT, k0 + 64, buf ^ 1) }               \
            for (int kk = 0; kk < 64; kk += 32) {                                  \
                bf16x8 af[4], bfr[4];                                              \
                int k4 = kk >> 3;                                                  \
                for (int i = 0; i < 4; ++i)                                        \
                    af[i]  = *(const bf16x8*)&As[buf][mb + i * 16 + r][((k4 + quad) ^ (r & 7)) * 8]; \
                for (int j = 0; j < 4; ++j)                                        \
                    bfr[j] = *(const bf16x8*)&Bs[buf][nb + j * 16 + r][((k4 + quad) ^ (r & 7)) * 8]; \
                for (int i = 0; i < 4; ++i)                                        \
                    for (int j = 0; j < 4; ++j)                                    \
                        acc[i][j] = __builtin_amdgcn_mfma_f32_16x16x32_bf16(af[i], bfr[j], acc[i][j], 0, 0, 0); \
            }                                                                      \
            buf ^= 1;                                                              \
        }                                                                          \
    }

// ---------------------------------------------------- out-projection GEMM
__global__ __launch_bounds__(256) void gemm_bt_kernel(const ushort_t* __restrict__ A,
                                                      const ushort_t* __restrict__ BT,
                                                      const float* __restrict__ bias,
                                                      float* __restrict__ C,
                                                      int M, int N, int K) {
    __shared__ ushort_t As[2][128][64];
    __shared__ ushort_t Bs[2][128][64];
    const int bm = blockIdx.x * 128, bn = blockIdx.y * 128;
    const int t = threadIdx.x;
    const int w = t >> 6, lane = t & 63, quad = lane >> 4, r = lane & 15;
    const int mb = (w >> 1) * 64, nb = (w & 1) * 64;
    f32x4 acc[4][4] = {};
    GEMM_MAIN_LOOP(A, BT, K)
    for (int i = 0; i < 4; ++i)
        for (int j = 0; j < 4; ++j)
            for (int reg = 0; reg < 4; ++reg) {
                int row = bm + mb + i * 16 + quad * 4 + reg;
                int col = bn + nb + j * 16 + r;
                C[(size_t)row * N + col] = acc[i][j][reg] + bias[col];
            }
}

// ------------------------------------- QKV GEMM + fused RMSNorm/rearrange
// N-tile 128 == one head group. g = blockIdx.y: 0..15 -> Q (rmsnorm*q_scale*SM),
// 16..19 -> K (rmsnorm*k_scale), 20..23 -> V transposed directly to Vt [nk][d][l].
__global__ __launch_bounds__(256) void gemm_qkv_kernel(const ushort_t* __restrict__ A,
                                                       const ushort_t* __restrict__ BT,
                                                       const float* __restrict__ bias,
                                                       const float* __restrict__ q_scale,
                                                       const float* __restrict__ k_scale,
                                                       ushort_t* __restrict__ Q,
                                                       ushort_t* __restrict__ Kb,
                                                       ushort_t* __restrict__ Vt) {
    __shared__ ushort_t As[2][128][64];
    __shared__ ushort_t Bs[2][128][64];
    const int K = D_MODEL;
    const int bm = blockIdx.x * 128, bn = blockIdx.y * 128;
    const int t = threadIdx.x;
    const int w = t >> 6, lane = t & 63, quad = lane >> 4, r = lane & 15;
    const int mb = (w >> 1) * 64, nb = (w & 1) * 64;
    f32x4 acc[4][4] = {};
    GEMM_MAIN_LOOP(A, BT, K)

    const int g = blockIdx.y;
    float bj[4];
    for (int j = 0; j < 4; ++j) bj[j] = bias[bn + nb + j * 16 + r];
    for (int i = 0; i < 4; ++i)
        for (int j = 0; j < 4; ++j)
            for (int reg = 0; reg < 4; ++reg) acc[i][j][reg] += bj[j];

    const int n = bm >> 11, lb = bm & 2047;
    if (g < 20) {
        __syncthreads();                              // LDS free; reuse for ssum
        float* ssum = (float*)&As[0][0][0];           // [2][128]
        for (int i = 0; i < 4; ++i)
            for (int reg = 0; reg < 4; ++reg) {
                float p = 0.f;
                for (int j = 0; j < 4; ++j) p += acc[i][j][reg] * acc[i][j][reg];
                p += __shfl_xor(p, 1); p += __shfl_xor(p, 2);
                p += __shfl_xor(p, 4); p += __shfl_xor(p, 8);
                if (r == 0) ssum[(w & 1) * 128 + mb + i * 16 + quad * 4 + reg] = p;
            }
        __syncthreads();
        const float* scp = (g < 16) ? q_scale : k_scale;
        const float smul = (g < 16) ? SM_SCALE : 1.0f;
        float scj[4];
        for (int j = 0; j < 4; ++j) scj[j] = scp[nb + j * 16 + r];
        ushort_t* dst = (g < 16) ? (Q  + (size_t)(n * 16 + g) * SEQ * HD)
                                 : (Kb + (size_t)(n * 4 + g - 16) * SEQ * HD);
        for (int i = 0; i < 4; ++i)
            for (int reg = 0; reg < 4; ++reg) {
                int rl = mb + i * 16 + quad * 4 + reg;
                float ss = ssum[rl] + ssum[128 + rl];
                float iv = rsqrtf(ss * (1.0f / 128.0f) + 1e-6f) * smul;
                size_t lrow = lb + rl;
                for (int j = 0; j < 4; ++j) {
                    int d = nb + j * 16 + r;
                    dst[lrow * HD + d] = f2bf(acc[i][j][reg] * iv * scj[j]);
                }
            }
    } else {
        // V: write transposed directly, packing 4 consecutive l per lane (8 B)
        ushort_t* dstT = Vt + (size_t)(n * 4 + g - 20) * HD * SEQ;
        for (int i = 0; i < 4; ++i)
            for (int j = 0; j < 4; ++j) {
                int d = nb + j * 16 + r;
                ushort_t o[4];
                for (int reg = 0; reg < 4; ++reg) o[reg] = f2bf(acc[i][j][reg]);
                *(uint2*)&dstT[(size_t)d * SEQ + lb + mb + i * 16 + quad * 4] = *(uint2*)o;
            }
    }
}

// --------------------------------------------------- flash causal attention
// grid (8, 16, 4), block 256 (4 waves). Wave owns 32 q-rows (2 strips of 16);
// block tile 128 q-rows. Paired q-tiles {pid, 15-pid}: 34 steps/block, balanced.
// K AND V double-buffered; ONE barrier per step (GEMM dbuf pattern): prefetch
// (ct+1) issued at step start has all of QK+softmax+PV to complete before the
// next barrier's vmcnt drain. LDS = 32K + 32K + 16K = 80 KB -> 2 blocks/CU
// (8 waves/CU). VGPR kept ~170 (32 rows/wave) — R4 showed 64 rows/wave blows
// the register file (256 VGPR, 1 wave/SIMD, 3.5x regression).
__global__ __launch_bounds__(256, 2) void attn_kernel(const ushort_t* __restrict__ Q,
                                                      const ushort_t* __restrict__ K,
                                                      const ushort_t* __restrict__ Vt,
                                                      ushort_t* __restrict__ Y) {
    const int pid = blockIdx.x, h = blockIdx.y, n = blockIdx.z;
    const int kvh = h >> 2;
    const ushort_t* Qp = Q  + (size_t)(n * N_HEADS + h) * SEQ * HD;
    const ushort_t* Kp = K  + (size_t)(n * N_KV + kvh) * SEQ * HD;
    const ushort_t* Vp = Vt + (size_t)(n * N_KV + kvh) * HD * SEQ;   // [d][l]

    __shared__ ushort_t Ks[2][64][128];   // 32 KB, chunk-swizzled, dbuf
    __shared__ ushort_t Vts[2][128][64];  // 32 KB, chunk-swizzled ([d][key]), dbuf
    __shared__ ushort_t Ps[128][64];      // 16 KB, row-chunk-xor swizzled

    const int t = threadIdx.x, w = t >> 6, lane = t & 63, quad = lane >> 4, r = lane & 15;

#define ATTN_STAGE(ct, b)                                                           \
    for (int i = 0; i < 4; ++i) {                                                   \
        int ci = (w * 4 + i) * 64 + lane;                                           \
        {   /* K tile 64x128: 16 chunks/row */                                      \
            int row = ci >> 4, c = ci & 15, cg = c ^ (row & 7);                     \
            gload16(&Kp[(size_t)((ct) * 64 + row) * HD + cg * 8],                   \
                    &Ks[b][0][0] + (w * 4 + i) * 512);                              \
        }                                                                           \
        {   /* Vt tile 128x64: 8 chunks/row */                                      \
            int row = ci >> 3, c = ci & 7, cg = c ^ (row & 7);                      \
            gload16(&Vp[(size_t)row * SEQ + (ct) * 64 + cg * 8],                    \
                    &Vts[b][0][0] + (w * 4 + i) * 512);                             \
        }                                                                           \
    }

    for (int rep = 0; rep < 2; ++rep) {
        const int qt = rep ? (15 - pid) : pid;
        const int q0 = qt * 128;

        __syncthreads();   // prev rep's LDS reads done before restaging buf 0
        ATTN_STAGE(0, 0)

        // Q fragments straight from global (A-layout is contiguous 16B/lane)
        bf16x8 aq[2][4];
        for (int s = 0; s < 2; ++s)
            for (int kc = 0; kc < 4; ++kc)
                aq[s][kc] = *(const bf16x8*)&Qp[(size_t)(q0 + w * 32 + s * 16 + r) * HD + kc * 32 + quad * 8];

        f32x4 oacc[2][8] = {};
        float lsum[2][4] = {};
        const int nct = 2 * qt + 2;
        int buf = 0;

        for (int ct = 0; ct < nct; ++ct) {
            __syncthreads();   // drains DMA into buf; all reads of buf^1 done
            if (ct + 1 < nct) { ATTN_STAGE(ct + 1, buf ^ 1) }

            // skip tiles entirely above the causal boundary for this wave
            if (ct * 64 <= q0 + w * 32 + 31) {
                // S strips [2 x 16 x 64]: QK^T (scale folded into Q)
                f32x4 sacc[2][4] = {};
                for (int kc = 0; kc < 4; ++kc)
                    for (int jt = 0; jt < 4; ++jt) {
                        bf16x8 bk = *(const bf16x8*)&Ks[buf][jt * 16 + r][((kc * 4 + quad) ^ (r & 7)) * 8];
                        sacc[0][jt] = __builtin_amdgcn_mfma_f32_16x16x32_bf16(aq[0][kc], bk, sacc[0][jt], 0, 0, 0);
                        sacc[1][jt] = __builtin_amdgcn_mfma_f32_16x16x32_bf16(aq[1][kc], bk, sacc[1][jt], 0, 0, 0);
                    }

                // fixed-max softmax; P truncated bf16; row-chunk-xor swizzle
                const bool diag = (ct >= 2 * qt);
                for (int s = 0; s < 2; ++s)
                    for (int reg = 0; reg < 4; ++reg) {
                        int prow = w * 32 + s * 16 + quad * 4 + reg;
                        int qg = q0 + prow;
                        float rs = 0.f;
                        for (int jt = 0; jt < 4; ++jt) {
                            float sv = sacc[s][jt][reg];
                            if (diag && (ct * 64 + jt * 16 + r) > qg) sv = -1e30f;
                            float p = __expf(sv);
                            rs += p;
                            int colp = ((((jt * 2 + (r >> 3)) ^ prow) & 7) << 3) | (r & 7);
                            Ps[prow][colp] = (ushort_t)(__float_as_uint(p) >> 16);
                        }
                        lsum[s][reg] += rs;
                    }

                // PV: O[2x16x128] += P @ V ; bv shared by strips; Ps wave-private
                for (int kk = 0; kk < 64; kk += 32) {
                    bf16x8 pa[2];
                    for (int s = 0; s < 2; ++s) {
                        int row = w * 32 + s * 16 + r;
                        pa[s] = *(const bf16x8*)&Ps[row][((((kk >> 3) + quad) ^ row) & 7) * 8];
                    }
                    for (int dt = 0; dt < 8; ++dt) {
                        bf16x8 bv = *(const bf16x8*)&Vts[buf][dt * 16 + r][((((kk >> 3) + quad) ^ (r & 7)) & 7) * 8];
                        oacc[0][dt] = __builtin_amdgcn_mfma_f32_16x16x32_bf16(pa[0], bv, oacc[0][dt], 0, 0, 0);
                        oacc[1][dt] = __builtin_amdgcn_mfma_f32_16x16x32_bf16(pa[1], bv, oacc[1][dt], 0, 0, 0);
                    }
                }
            }
            buf ^= 1;
        }

        // epilogue: end-of-loop row-sum reduction, then Y
        for (int s = 0; s < 2; ++s)
            for (int reg = 0; reg < 4; ++reg) {
                float sv = lsum[s][reg];
                for (int m = 1; m < 16; m <<= 1) sv += __shfl_xor(sv, m);
                float invl = 1.0f / sv;
                int lrow = q0 + w * 32 + s * 16 + quad * 4 + reg;
                size_t base = ((size_t)(n * SEQ + lrow)) * D_MODEL + h * HD;
                for (int dt = 0; dt < 8; ++dt)
                    Y[base + dt * 16 + r] = f2bf(oacc[s][dt][reg] * invl);
            }
    }
#undef ATTN_STAGE
}

// ------------------------------------------------------------------ launch
extern "C" void kernel_launch(void* const* d_in, const int* in_sizes, int n_in,
                              void* d_out, int out_size, void* d_ws, size_t ws_size,
                              hipStream_t stream) {
    const float* x       = (const float*)d_in[0];
    const float* Wqkv    = (const float*)d_in[1];
    const float* bqkv    = (const float*)d_in[2];
    const float* q_scale = (const float*)d_in[3];
    const float* k_scale = (const float*)d_in[4];
    const float* Wout    = (const float*)d_in[5];
    const float* bout    = (const float*)d_in[6];
    float* out = (float*)d_out;

    ushort_t* xb  = (ushort_t*)d_ws;                        // 8192*2048 (later: y)
    ushort_t* WT  = xb  + (size_t)MROWS * D_MODEL;          // 3072*2048 (later: WoutT)
    ushort_t* Qb  = WT  + (size_t)NQKV * D_MODEL;           // 4*16*2048*128
    ushort_t* Kb  = Qb  + (size_t)NB * N_HEADS * SEQ * HD;  // 4*4*2048*128
    ushort_t* Vtb = Kb  + (size_t)NB * N_KV * SEQ * HD;     // 4*4*128*2048

    conv_x_kernel<<<MROWS * D_MODEL / 1024, 256, 0, stream>>>(x, xb, MROWS * D_MODEL);
    conv_wt_kernel<<<dim3(NQKV / 32, D_MODEL / 32), dim3(32, 8), 0, stream>>>(Wqkv, WT, D_MODEL, NQKV);
    gemm_qkv_kernel<<<dim3(MROWS / 128, NQKV / 128), 256, 0, stream>>>(xb, WT, bqkv, q_scale, k_scale, Qb, Kb, Vtb);
    conv_wt_kernel<<<dim3(D_MODEL / 32, D_MODEL / 32), dim3(32, 8), 0, stream>>>(Wout, WT, D_MODEL, D_MODEL);
    attn_kernel<<<dim3(8, N_HEADS, NB), 256, 0, stream>>>(Qb, Kb, Vtb, xb);
    gemm_bt_kernel<<<dim3(MROWS / 128, D_MODEL / 128), 256, 0, stream>>>(xb, WT, bout, out, MROWS, D_MODEL, D_MODEL);
}